// Round 13
// baseline (281.032 us; speedup 1.0000x reference)
//
#include <hip/hip_runtime.h>
#include <hip/hip_bf16.h>

using bf16 = __hip_bfloat16;
using bf16x8 = __attribute__((ext_vector_type(8))) short;   // 8 bf16 = 4 VGPRs (MFMA A/B frag)
using f32x4  = __attribute__((ext_vector_type(4))) float;   // MFMA C/D frag (native vector)

#define B_    16
#define HIM   56
#define WIM   56
#define HD    512
#define NHEAD 8
#define DH    64
#define NTOK  (HIM*WIM)      // 3136
#define M_    (B_*NTOK)      // 50176
#define K49   49

// ---- async global->LDS, 16B per lane; LDS dest = wave-uniform base (+lane*16 by HW) ----
__device__ __forceinline__ void gload_lds16(const void* g, void* l) {
  __builtin_amdgcn_global_load_lds(
      (__attribute__((address_space(1))) const void*)g,
      (__attribute__((address_space(3))) void*)l, 16, 0, 0);
}

// ---------------- kernel: fp32 -> bf16 convert (vectorized, 8 elems/thread) ----------------
__global__ __launch_bounds__(256) void cvt_x_kernel(const float* __restrict__ in,
                                                    bf16* __restrict__ out) {
  size_t i = ((size_t)blockIdx.x * 256 + threadIdx.x) * 8;
  float4 a = *(const float4*)(in + i);
  float4 b = *(const float4*)(in + i + 4);
  union { uint4 v; bf16 h[8]; } o;
  o.h[0] = __float2bfloat16(a.x); o.h[1] = __float2bfloat16(a.y);
  o.h[2] = __float2bfloat16(a.z); o.h[3] = __float2bfloat16(a.w);
  o.h[4] = __float2bfloat16(b.x); o.h[5] = __float2bfloat16(b.y);
  o.h[6] = __float2bfloat16(b.z); o.h[7] = __float2bfloat16(b.w);
  *(uint4*)(out + i) = o.v;
}

// ---------------- kernel: W (K x N) -> Wt (N x K) bf16 ----------------
__global__ __launch_bounds__(256) void cvt_transpose_kernel(const float* __restrict__ in,
                                                            bf16* __restrict__ out,
                                                            int K, int N) {
  int idx = blockIdx.x * 256 + threadIdx.x;   // grid covers K*N exactly
  int k = idx / N, n = idx - k * N;
  out[(size_t)n * K + k] = __float2bfloat16(in[idx]);
}

// ============================================================================
// 128x256-tile GEMM, B-OPERAND DIRECT FROM L2 (no LDS for B).
// Rationale (r12 post-mortem): all LDS-both-operands variants hit the same
// ~1500 cyc/kslice LDS-port floor (reads amplified 4x/2x across waves) ==
// the invariant behind 8 flat rounds. B panels (<=1.5 MB) fit in each XCD L2,
// so B-frags are buffer-loaded straight to registers (double-buffered, loaded
// one kslice ahead; L2 hit ~200cyc << kslice). Only A is LDS-staged:
// LDS pipe ~900 cyc < MFMA 1242 cyc per CU -> MFMA becomes the critical pipe.
// 4 waves (1M x 4N, wave tile 128x64), acc=128 VGPR, ~212 total -> 2 w/SIMD.
// LDS = 4-slot A ring x 8KB = 32 KB -> 2 INDEPENDENT blocks/CU: cross-block
// waves on each SIMD overlap MFMA with the other block's stage/barrier.
// vmcnt regions per kslice j: {A(j+3) x2 gload_lds, B(j+2) x4 global} between
// asm walls; worst-case-reorder-safe gates: prologue vmcnt(4) ("all of
// {A0,A1,A2,B0} done"), steady vmcnt(6), tail 6,4,0.
// XOR swizzle slot^((row>>1)&3) on A (rounds 1-12: 0 bank conflicts).
// mfma(b,a) operand swap -> packed 8B/16B NT epilogue stores (WRITE ideal).
// ============================================================================
template<int N, bool OUT_BF16, bool BIAS>
__global__ __launch_bounds__(256, 2) void gemm_bl2_kernel(
    const bf16* __restrict__ A,    // M x 512 row-major
    const bf16* __restrict__ Bt,   // N x 512 row-major (fits L2)
    void* __restrict__ Cp,
    const float* __restrict__ bias,
    int NBX)
{
  constexpr int K = 512;
  __shared__ alignas(16) bf16 ldsA[4][128 * 32];   // 4 slots x 8 KB = 32 KiB
  const int tid  = threadIdx.x;
  const int lane = tid & 63, wid = tid >> 6;        // 4 waves, wn = wid
  const int l15  = lane & 15, kq = lane >> 4;
  const int cpx = gridDim.x >> 3;                   // XCD swizzle (grid % 8 == 0)
  const int wg  = (blockIdx.x & 7) * cpx + (blockIdx.x >> 3);
  const int by  = wg / NBX, bx = wg - by * NBX;
  const long arow0 = (long)by * 128;
  const long bcol0 = (long)bx * 256;

  // stage A kslice j: 128 rows x 32 cols = 8 KB, 2 gload_lds per thread
  auto stageA = [&](int j) {
    const bf16* g = A + arow0 * K + j * 32;
    bf16* lb = &ldsA[j & 3][0];
#pragma unroll
    for (int c = 0; c < 2; ++c) {
      int s   = c * 256 + tid;          // 16B-slot id (512 per kslice)
      int row = s >> 2, sl = s & 3;
      int gs  = sl ^ ((row >> 1) & 3);  // pre-swizzled global source slot
      gload_lds16((const char*)(g + (long)row * K) + gs * 16,
                  lb + (c * 256 + wid * 64) * 8);   // wave-uniform dest
    }
  };
  auto rdA = [&](int slot, int mt) -> bf16x8 {
    int rr = mt * 16 + l15;
    return *(const bf16x8*)&ldsA[slot][rr * 32 + ((kq ^ ((rr >> 1) & 3)) << 3)];
  };
  // B fragment base: row (bcol0 + wn*64 + nt*16 + l15), 16B at k-offset kq*16
  const bf16* Bbase = Bt + (bcol0 + wid * 64 + l15) * (long)K + kq * 8;

  f32x4 acc[8][4] = {};   // rows arow0+mt*16+l15, cols bcol0+wn*64+nt*16+kq*4+r
  bf16x8 bf0[4], bf1[4];

  // prologue: A(0..2) to LDS ring; B(0)->bf0, wall, B(1)->bf1
  stageA(0); stageA(1); stageA(2);
#pragma unroll
  for (int nt = 0; nt < 4; ++nt) bf0[nt] = *(const bf16x8*)(Bbase + (long)nt * 16 * K);
  asm volatile("" ::: "memory");
#pragma unroll
  for (int nt = 0; nt < 4; ++nt) bf1[nt] = *(const bf16x8*)(Bbase + (long)nt * 16 * K + 32);

#define KS(SLOT, BF, VM, DOST, JST, DOLD, JLD) {                              \
    asm volatile("s_waitcnt vmcnt(" VM ")" ::: "memory");                     \
    __builtin_amdgcn_s_barrier();                                             \
    bf16x8 af[8];                                                             \
    _Pragma("unroll")                                                         \
    for (int mt = 0; mt < 8; ++mt) af[mt] = rdA(SLOT, mt);                    \
    if (DOST) stageA(JST);                                                    \
    __builtin_amdgcn_s_setprio(1);                                            \
    _Pragma("unroll")                                                         \
    for (int mt = 0; mt < 8; ++mt)                                            \
      _Pragma("unroll")                                                       \
      for (int nt = 0; nt < 4; ++nt)                                          \
        acc[mt][nt] = __builtin_amdgcn_mfma_f32_16x16x32_bf16(BF[nt], af[mt], \
                                                              acc[mt][nt], 0, 0, 0); \
    __builtin_amdgcn_s_setprio(0);                                            \
    if (DOLD) {                                                               \
      _Pragma("unroll")                                                       \
      for (int nt = 0; nt < 4; ++nt)                                          \
        BF[nt] = *(const bf16x8*)(Bbase + (long)nt * 16 * K + (JLD) * 32);    \
    }                                                                         \
  }

  // j=0 (slot0, bf0): top gate vmcnt(4) == "all of {A0,A1,A2,B0} landed"
  KS(0, bf0, "4", 1, 3, 1, 2);
  // j=1..12: slots 1,2,3,0 / parity 1,0,1,0 per group; steady vmcnt(6)
#pragma unroll 1
  for (int jo = 1; jo <= 9; jo += 4) {
    KS(1, bf1, "6", 1, jo + 3, 1, jo + 2);
    KS(2, bf0, "6", 1, jo + 4, 1, jo + 3);
    KS(3, bf1, "6", 1, jo + 5, 1, jo + 4);
    KS(0, bf0, "6", 1, jo + 6, 1, jo + 5);
  }
  // tail: j=13 (loads B15), 14, 15
  KS(1, bf1, "6", 0, 0, 1, 15);
  KS(2, bf0, "4", 0, 0, 0, 0);
  KS(3, bf1, "0", 0, 0, 0, 0);
#undef KS

  // epilogue: lane holds rows arow0+mt*16+l15, cols ccol0+nt*16+kq*4+{0..3}
  const long ccol0 = bcol0 + wid * 64 + kq * 4;
#pragma unroll
  for (int mt = 0; mt < 8; ++mt) {
    long row = arow0 + mt * 16 + l15;
#pragma unroll
    for (int nt = 0; nt < 4; ++nt) {
      long col = ccol0 + nt * 16;
      if (OUT_BF16) {
        union { unsigned long long u; unsigned short h[4]; } pk;
#pragma unroll
        for (int r = 0; r < 4; ++r) {
          bf16 hh = __float2bfloat16(acc[mt][nt][r]);
          pk.h[r] = *(unsigned short*)&hh;
        }
        __builtin_nontemporal_store(pk.u,
            (unsigned long long*)((bf16*)Cp + row * N + col));
      } else {
        f32x4 o = acc[mt][nt];
        if (BIAS) {
          o[0] += bias[col];     o[1] += bias[col + 1];
          o[2] += bias[col + 2]; o[3] += bias[col + 3];
        }
        __builtin_nontemporal_store(o, (f32x4*)((float*)Cp + row * N + col));
      }
    }
  }
}

// ---------------- kernel: windowed attention, one WG per (b, window p, head g) ------------
// round-5 v1 + PV operand swap (r12, verified): packed 8B output stores.
__global__ __launch_bounds__(256) void attn_win_kernel(
    const bf16* __restrict__ qkv, const float* __restrict__ rb, bf16* __restrict__ outa)
{
  __shared__ alignas(16) bf16 Qs[64 * 72];  // [token][chan], stride 72 (144B -> 2-way free)
  __shared__ alignas(16) bf16 Ks[64 * 72];
  __shared__ alignas(16) bf16 Vt[64 * 72];  // transposed: [chan][token]
  __shared__ alignas(16) bf16 Ps[64 * 72];  // probabilities [q][k]
  const int tid = threadIdx.x, lane = tid & 63, wid = tid >> 6;
  const int p = blockIdx.x, g = blockIdx.y, b = blockIdx.z;
  const int sh = p >> 3, sw = p & 7;
  const size_t nb = (size_t)b * NTOK;
  const int c8 = (tid & 7) * 8;

  // stage Q,K row-major + V transposed; zero-fill pad tokens 49..63
#pragma unroll
  for (int it = 0; it < 2; ++it) {
    int t = (tid >> 3) + it * 32;
    uint4 vq = {0, 0, 0, 0}, vk = vq, vv = vq;
    if (t < K49) {
      int ph = t / 7, pw = t - ph * 7;
      int n = (sh * 7 + ph) * WIM + sw * 7 + pw;
      const bf16* src = qkv + (nb + n) * 1536 + g * 64 + c8;
      vq = *(const uint4*)(src);
      vk = *(const uint4*)(src + 512);
      vv = *(const uint4*)(src + 1024);
    }
    *(uint4*)&Qs[t * 72 + c8] = vq;
    *(uint4*)&Ks[t * 72 + c8] = vk;
    union { uint4 u; unsigned short s[8]; } uv; uv.u = vv;
    unsigned short* vt16 = (unsigned short*)Vt;
#pragma unroll
    for (int e = 0; e < 8; ++e) vt16[(c8 + e) * 72 + t] = uv.s[e];
  }
  __syncthreads();

  const int l15 = lane & 15, kq = lane >> 4;
  // ---- S = Q K^T (wave w owns q rows 16w..16w+15; 4 col tiles) ----
  bf16x8 aq[2];
#pragma unroll
  for (int kk = 0; kk < 2; ++kk)
    aq[kk] = *(const bf16x8*)&Qs[(wid * 16 + l15) * 72 + kk * 32 + kq * 8];
  float sv[4][4];   // [ct][r]
#pragma unroll
  for (int ct = 0; ct < 4; ++ct) {
    f32x4 acc = {0.f, 0.f, 0.f, 0.f};
#pragma unroll
    for (int kk = 0; kk < 2; ++kk) {
      bf16x8 bk = *(const bf16x8*)&Ks[(ct * 16 + l15) * 72 + kk * 32 + kq * 8];
      acc = __builtin_amdgcn_mfma_f32_16x16x32_bf16(aq[kk], bk, acc, 0, 0, 0);
    }
    int kcol = ct * 16 + l15;
#pragma unroll
    for (int r = 0; r < 4; ++r) {
      int q = wid * 16 + kq * 4 + r;
      float bias = (q < K49 && kcol < K49) ? rb[((size_t)g * K49 + q) * K49 + kcol] : 0.f;
      float v = (acc[r] + bias) * 0.125f;          // (S + rel_bias) * dh^-0.5
      sv[ct][r] = (kcol < K49) ? v : -1e30f;       // mask pad keys
    }
  }
  // ---- softmax over keys (row q lives in the 16 lanes sharing kq) ----
#pragma unroll
  for (int r = 0; r < 4; ++r) {
    float m = fmaxf(fmaxf(sv[0][r], sv[1][r]), fmaxf(sv[2][r], sv[3][r]));
#pragma unroll
    for (int d = 1; d < 16; d <<= 1) m = fmaxf(m, __shfl_xor(m, d));
    float e0 = __expf(sv[0][r] - m), e1 = __expf(sv[1][r] - m);
    float e2 = __expf(sv[2][r] - m), e3 = __expf(sv[3][r] - m);
    float s = e0 + e1 + e2 + e3;
#pragma unroll
    for (int d = 1; d < 16; d <<= 1) s += __shfl_xor(s, d);
    float inv = 1.0f / s;
    int q = wid * 16 + kq * 4 + r;
    Ps[q * 72 +  0 + l15] = __float2bfloat16(e0 * inv);
    Ps[q * 72 + 16 + l15] = __float2bfloat16(e1 * inv);
    Ps[q * 72 + 32 + l15] = __float2bfloat16(e2 * inv);
    Ps[q * 72 + 48 + l15] = __float2bfloat16(e3 * inv);
  }
  __syncthreads();
  // ---- O = P V, swapped operands: D[row=channel(kq*4+r)][col=q(l15)] ----
  bf16x8 ap[2];
#pragma unroll
  for (int kk = 0; kk < 2; ++kk)
    ap[kk] = *(const bf16x8*)&Ps[(wid * 16 + l15) * 72 + kk * 32 + kq * 8];
  f32x4 accO[4] = {};
#pragma unroll
  for (int ct = 0; ct < 4; ++ct)
#pragma unroll
    for (int kk = 0; kk < 2; ++kk) {
      bf16x8 bv = *(const bf16x8*)&Vt[(ct * 16 + l15) * 72 + kk * 32 + kq * 8];
      accO[ct] = __builtin_amdgcn_mfma_f32_16x16x32_bf16(bv, ap[kk], accO[ct], 0, 0, 0);
    }
  int q = wid * 16 + l15;
  if (q < K49) {
    int ph = q / 7, pw = q - ph * 7;
    bf16* dst = outa + (nb + (sh * 7 + ph) * WIM + sw * 7 + pw) * HD + g * 64 + kq * 4;
#pragma unroll
    for (int ct = 0; ct < 4; ++ct) {
      union { unsigned long long u; unsigned short h[4]; } pk;
#pragma unroll
      for (int r = 0; r < 4; ++r) {
        bf16 hh = __float2bfloat16(accO[ct][r]);
        pk.h[r] = *(unsigned short*)&hh;
      }
      *(unsigned long long*)(dst + ct * 16) = pk.u;
    }
  }
}

// ---------------- launch ----------------
extern "C" void kernel_launch(void* const* d_in, const int* in_sizes, int n_in,
                              void* d_out, int out_size, void* d_ws, size_t ws_size,
                              hipStream_t stream) {
  (void)in_sizes; (void)n_in; (void)out_size;
  const float* x     = (const float*)d_in[0];
  // d_in[1] = mask: all-False with zero padding (56 % 7 == 0) -> no-op, skipped
  const float* wqkv  = (const float*)d_in[2];
  const float* wproj = (const float*)d_in[3];
  const float* bproj = (const float*)d_in[4];
  const float* rb    = (const float*)d_in[5];
  // d_in[6], d_in[7] = H, W (56, 56) constants

  // workspace layout (207,618,048 bytes total)
  char* ws = (char*)d_ws;
  bf16* x_bf    = (bf16*)(ws);              // 51,380,224 B ; reused as attnout after GEMM1
  bf16* wqkv_t  = (bf16*)(ws + 51380224);   //  1,572,864 B
  bf16* wproj_t = (bf16*)(ws + 52953088);   //    524,288 B
  bf16* qkv     = (bf16*)(ws + 53477376);   // 154,140,672 B
  bf16* attno   = x_bf;
  float* out    = (float*)d_out;
  if (ws_size < 207618048) return;  // fail visibly rather than corrupt

  cvt_x_kernel<<<dim3(12544), 256, 0, stream>>>(x, x_bf);                       // 50176*512/8/256
  cvt_transpose_kernel<<<dim3(3072), 256, 0, stream>>>(wqkv, wqkv_t, 512, 1536);
  cvt_transpose_kernel<<<dim3(1024), 256, 0, stream>>>(wproj, wproj_t, 512, 512);
  // GEMM1: 392 M-tiles x 6 N-tiles = 2352 blocks (2352 % 8 == 0), 2 blocks/CU
  gemm_bl2_kernel<1536, true, false><<<dim3(2352), 256, 0, stream>>>(
      x_bf, wqkv_t, (void*)qkv, nullptr, 6);
  attn_win_kernel<<<dim3(64, NHEAD, B_), 256, 0, stream>>>(qkv, rb, attno);
  // GEMM2: 392 x 2 = 784 blocks (784 % 8 == 0)
  gemm_bl2_kernel<512, false, true><<<dim3(784), 256, 0, stream>>>(
      attno, wproj_t, (void*)out, bproj, 2);
}